// Round 5
// baseline (458.169 us; speedup 1.0000x reference)
//
#include <hip/hip_runtime.h>
#include <hip/hip_bf16.h>

#define NRBF 20
#define FEATC 128

typedef __attribute__((ext_vector_type(8))) short short8;
typedef __attribute__((ext_vector_type(4))) float float4v;

__device__ __forceinline__ float bf2f(unsigned short u) {
    return __uint_as_float(((unsigned)u) << 16);
}
__device__ __forceinline__ unsigned short f2bf(float f) {
    unsigned u = __float_as_uint(f);
    u += 0x7FFF + ((u >> 16) & 1);   // round-to-nearest-even
    return (unsigned short)(u >> 16);
}
__device__ __forceinline__ float ldin(const void* p, size_t idx, int isbf) {
    return isbf ? bf2f(((const unsigned short*)p)[idx]) : ((const float*)p)[idx];
}
__device__ __forceinline__ void stout(void* p, size_t idx, float v, int isbf) {
    if (isbf) ((unsigned short*)p)[idx] = f2bf(v);
    else      ((float*)p)[idx] = v;
}

// ---------------- dtype detector ----------------
__global__ void detect_kernel(const void* __restrict__ xyz, int* __restrict__ flag) {
    if (threadIdx.x == 0 && blockIdx.x == 0) {
        const unsigned short* u = (const unsigned short*)xyz;
        int bad = 0;
        for (int k = 0; k < 256; k++) {
            unsigned e = (u[2 * k] >> 7) & 0xFF;
            if (e >= 0x90) bad++;
        }
        *flag = (bad > 8) ? 0 : 1;  // 1 = bf16, 0 = f32
    }
}

// ---------------- init: s_acc/s_hi/s_lo <- cg_s ----------------
__global__ void init_s_kernel(const void* __restrict__ cg_s,
                              float* __restrict__ s_acc,
                              unsigned short* __restrict__ s_hi,
                              unsigned short* __restrict__ s_lo, int n,
                              const int* __restrict__ flagp) {
    int isbf = *flagp;
    int idx = blockIdx.x * blockDim.x + threadIdx.x;
    if (idx >= n) return;
    float v = ldin(cg_s, idx, isbf);
    s_acc[idx] = v;
    unsigned short hi = f2bf(v);
    s_hi[idx] = hi;
    s_lo[idx] = f2bf(v - bf2f(hi));
}

// ---------------- per-edge geometry (+ fused degree count) ----------------
__global__ void geom_kernel(const void* __restrict__ xyz,
                            const int* __restrict__ nbr,
                            float* __restrict__ unitv,
                            unsigned short* __restrict__ rbfb,
                            float* __restrict__ env,
                            int* __restrict__ deg, int E,
                            const int* __restrict__ flagp) {
    int isbf = *flagp;
    int e = blockIdx.x * blockDim.x + threadIdx.x;
    if (e >= E) return;
    int i = nbr[2 * e], j = nbr[2 * e + 1];
    float dx = ldin(xyz, 3 * j,     isbf) - ldin(xyz, 3 * i,     isbf);
    float dy = ldin(xyz, 3 * j + 1, isbf) - ldin(xyz, 3 * i + 1, isbf);
    float dz = ldin(xyz, 3 * j + 2, isbf) - ldin(xyz, 3 * i + 2, isbf);
    float d2 = dx * dx + dy * dy + dz * dz + 3e-15f;
    float dist = sqrtf(d2);
    constexpr float PI = 3.14159265358979323846f;
    float ev = (dist < 5.0f) ? 0.5f * (cosf(PI * dist * 0.2f) + 1.0f) : 0.0f;
    env[e] = ev;
    if (ev == 0.0f) return;          // inactive edge: nothing else ever read
    atomicAdd(&deg[i], 1);
    float inv = 1.0f / dist;
    unitv[3 * e] = dx * inv; unitv[3 * e + 1] = dy * inv; unitv[3 * e + 2] = dz * inv;
    constexpr double EM5 = 0.006737946999085467;  // exp(-5)
    constexpr float MU0 = (float)EM5;
    constexpr float DMU = (float)((1.0 - EM5) / 19.0);
    constexpr float BETA = (float)(1.0 / ((0.1 * (1.0 - EM5)) * (0.1 * (1.0 - EM5))));
    float ed = expf(-dist);
    #pragma unroll
    for (int k = 0; k < NRBF; k++) {
        float dmu = ed - (MU0 + k * DMU);
        rbfb[(size_t)e * NRBF + k] = f2bf(ev * expf(-BETA * dmu * dmu));  // env folded in
    }
}

// ---------------- CSR: scan + scatter ----------------
__global__ void scan_kernel(int* __restrict__ deg, int* __restrict__ rowptr, int N) {
    __shared__ int part[256];
    int t = threadIdx.x;
    int chunk = (N + 255) / 256;
    int lo = t * chunk, hi = min(lo + chunk, N);
    int s = 0;
    for (int i = lo; i < hi; i++) s += deg[i];
    part[t] = s;
    __syncthreads();
    for (int off = 1; off < 256; off <<= 1) {
        int v = (t >= off) ? part[t - off] : 0;
        __syncthreads();
        if (t >= off) part[t] += v;
        __syncthreads();
    }
    int base = (t == 0) ? 0 : part[t - 1];
    for (int i = lo; i < hi; i++) {
        rowptr[i] = base;
        int d = deg[i];
        deg[i] = base;   // deg becomes scatter cursor
        base += d;
    }
    if (t == 0) rowptr[N] = part[255];
}

__global__ void scatter_kernel(const int* __restrict__ nbr, const float* __restrict__ env,
                               int* __restrict__ cursor, int* __restrict__ elist, int E) {
    int e = blockIdx.x * blockDim.x + threadIdx.x;
    if (e >= E) return;
    if (env[e] != 0.0f) {
        int pos = atomicAdd(&cursor[nbr[2 * e]], 1);
        elist[pos] = e;
    }
}

// ---------------- weight-fragment prep (split-bf16, MFMA B-operand order) ----------
__global__ void prep_frags_kernel(const void* __restrict__ W1, const void* __restrict__ W2,
                                  unsigned short* __restrict__ B1hi, unsigned short* __restrict__ B1lo,
                                  unsigned short* __restrict__ B2hi, unsigned short* __restrict__ B2lo,
                                  const int* __restrict__ flagp) {
    int isbf = *flagp;
    int idx = blockIdx.x * blockDim.x + threadIdx.x;
    const int NW1 = 3 * 4 * 8 * 64;
    const int NW2 = 3 * 4 * 24 * 64;
    if (idx < NW1) {
        int lane = idx & 63;
        int t = idx >> 6;
        int nt = t % 8; t /= 8;
        int ks = t % 4; int l = t / 4;
        int n = lane & 15, quad = lane >> 4;
        int col = nt * 16 + n;
        size_t base = (size_t)l * 128 * 128;
        size_t fo = (size_t)idx * 8;
        #pragma unroll
        for (int j = 0; j < 8; j++) {
            int k = ks * 32 + quad * 8 + j;
            float v = ldin(W1, base + (size_t)k * 128 + col, isbf);
            unsigned short hi = f2bf(v);
            B1hi[fo + j] = hi;
            B1lo[fo + j] = f2bf(v - bf2f(hi));
        }
    } else if (idx < NW1 + NW2) {
        int i2 = idx - NW1;
        int lane = i2 & 63;
        int t = i2 >> 6;
        int nt = t % 24; t /= 24;
        int ks = t % 4; int l = t / 4;
        int n = lane & 15, quad = lane >> 4;
        int col = nt * 16 + n;
        size_t base = (size_t)l * 128 * 384;
        size_t fo = (size_t)i2 * 8;
        #pragma unroll
        for (int j = 0; j < 8; j++) {
            int k = ks * 32 + quad * 8 + j;
            float v = ldin(W2, base + (size_t)k * 384 + col, isbf);
            unsigned short hi = f2bf(v);
            B2hi[fo + j] = hi;
            B2lo[fo + j] = f2bf(v - bf2f(hi));
        }
    }
}

// ---------------- MFMA GEMM (split-bf16): C = act(A@B + bias) ----------------
template <int ACT, int OUTMODE>
__global__ __launch_bounds__(256) void mfma_gemm(
    const unsigned short* __restrict__ Ahi, const unsigned short* __restrict__ Alo,
    const unsigned short* __restrict__ Bhi, const unsigned short* __restrict__ Blo,
    const void* __restrict__ bias, size_t biasoff,
    unsigned short* __restrict__ out_hi, unsigned short* __restrict__ out_lo,
    int M, int Ncols, const int* __restrict__ flagp) {
    int isbf = *flagp;
    int tid = threadIdx.x;
    int wave = tid >> 6, lane = tid & 63;
    int m = lane & 15, quad = lane >> 4;
    int brow = blockIdx.x * 64 + wave * 16;
    int row = brow + m;
    int ntiles = Ncols >> 4;
    int ntg0 = blockIdx.y * 4;
    float4v acc[4] = {};
    short8 zero8 = {};
    #pragma unroll
    for (int ks = 0; ks < 4; ks++) {
        short8 ah = zero8, al = zero8;
        if (row < M) {
            size_t ao = (size_t)row * 128 + ks * 32 + quad * 8;
            ah = *reinterpret_cast<const short8*>(Ahi + ao);
            al = *reinterpret_cast<const short8*>(Alo + ao);
        }
        #pragma unroll
        for (int nt = 0; nt < 4; nt++) {
            size_t fo = (((size_t)ks * ntiles + ntg0 + nt) * 64 + lane) * 8;
            short8 bh = *reinterpret_cast<const short8*>(Bhi + fo);
            acc[nt] = __builtin_amdgcn_mfma_f32_16x16x32_bf16(ah, bh, acc[nt], 0, 0, 0);
            acc[nt] = __builtin_amdgcn_mfma_f32_16x16x32_bf16(al, bh, acc[nt], 0, 0, 0);
            if (!isbf) {
                short8 bl = *reinterpret_cast<const short8*>(Blo + fo);
                acc[nt] = __builtin_amdgcn_mfma_f32_16x16x32_bf16(ah, bl, acc[nt], 0, 0, 0);
            }
        }
    }
    #pragma unroll
    for (int nt = 0; nt < 4; nt++) {
        int col = blockIdx.y * 64 + nt * 16 + m;
        float bv = ldin(bias, biasoff + col, isbf);
        #pragma unroll
        for (int r = 0; r < 4; r++) {
            int orow = brow + quad * 4 + r;
            if (orow >= M) continue;
            float x = acc[nt][r] + bv;
            if (ACT) x = x / (1.0f + expf(-x));  // silu
            size_t oo = (size_t)orow * Ncols + col;
            unsigned short h = f2bf(x);
            out_hi[oo] = h;
            if (OUTMODE == 0) out_lo[oo] = f2bf(x - bf2f(h));
        }
    }
}

// ---------------- persistent node gather kernel ----------------
// Thread t owns features {t, t+128, t+256}; Wr cols hoisted once per block.
// L0: v_old==0, skip gather. LAST: write d_out directly.
template <int L0, int LAST>
__global__ __launch_bounds__(128) void node_kernel(
    const int* __restrict__ rowptr, const int* __restrict__ elist,
    const int* __restrict__ nbr, const float* __restrict__ env,
    const float* __restrict__ unitv, const unsigned short* __restrict__ rbfb,
    const unsigned short* __restrict__ phi,   // bf16 [N][384]
    const void* __restrict__ Wr, size_t wroff,
    const void* __restrict__ br, size_t broff,
    const float* __restrict__ v_old, const unsigned short* __restrict__ vh_old,
    float* __restrict__ s_acc,
    unsigned short* __restrict__ s_hi, unsigned short* __restrict__ s_lo,
    float* __restrict__ v_new, unsigned short* __restrict__ vh_new,
    void* __restrict__ out, int N, const int* __restrict__ flagp) {
    int isbf = *flagp;
    int tt = threadIdx.x;  // 0..127

    float wc0[NRBF], wc1[NRBF], wc2[NRBF];
    #pragma unroll
    for (int r = 0; r < NRBF; r++) {
        size_t base = wroff + (size_t)r * 384 + tt;
        wc0[r] = ldin(Wr, base,       isbf);
        wc1[r] = ldin(Wr, base + 128, isbf);
        wc2[r] = ldin(Wr, base + 256, isbf);
    }
    float bb0 = ldin(br, broff + tt,       isbf);
    float bb1 = ldin(br, broff + tt + 128, isbf);
    float bb2 = ldin(br, broff + tt + 256, isbf);

    for (int node = blockIdx.x; node < N; node += gridDim.x) {
        int start = __builtin_amdgcn_readfirstlane(rowptr[node]);
        int end   = __builtin_amdgcn_readfirstlane(rowptr[node + 1]);
        float dsv = 0.f, ax = 0.f, ay = 0.f, az = 0.f;
        for (int k = start; k < end; k++) {
            int e = __builtin_amdgcn_readfirstlane(elist[k]);
            int j = __builtin_amdgcn_readfirstlane(nbr[2 * e + 1]);
            float ev = env[e];
            float ux = unitv[3 * e], uy = unitv[3 * e + 1], uz = unitv[3 * e + 2];
            float w0 = ev * bb0, w1 = ev * bb1, w2 = ev * bb2;
            const unsigned int* rp = (const unsigned int*)(rbfb + (size_t)e * NRBF);
            #pragma unroll
            for (int r = 0; r < NRBF / 2; r++) {
                unsigned int pr = rp[r];
                float r0 = bf2f((unsigned short)(pr & 0xFFFF));
                float r1 = bf2f((unsigned short)(pr >> 16));
                w0 += r0 * wc0[2 * r] + r1 * wc0[2 * r + 1];
                w1 += r0 * wc1[2 * r] + r1 * wc1[2 * r + 1];
                w2 += r0 * wc2[2 * r] + r1 * wc2[2 * r + 1];
            }
            size_t jb = (size_t)j * 384;
            dsv += bf2f(phi[jb + tt]) * w0;
            float gv = bf2f(phi[jb + 128 + tt]) * w1;
            float gu = bf2f(phi[jb + 256 + tt]) * w2;
            if (L0) {
                ax += gu * ux; ay += gu * uy; az += gu * uz;
            } else {
                const unsigned short* vj = &vh_old[jb + (size_t)tt * 3];
                ax += gu * ux + gv * bf2f(vj[0]);
                ay += gu * uy + gv * bf2f(vj[1]);
                az += gu * uz + gv * bf2f(vj[2]);
            }
        }
        size_t so = (size_t)node * 128 + tt;
        float snew = s_acc[so] + dsv;
        size_t ib = (size_t)node * 384 + (size_t)tt * 3;
        float vx = L0 ? ax : v_old[ib]     + ax;
        float vy = L0 ? ay : v_old[ib + 1] + ay;
        float vz = L0 ? az : v_old[ib + 2] + az;
        if (LAST) {
            stout(out, so, snew, isbf);
            size_t ob = (size_t)N * 128 + ib;
            stout(out, ob,     vx, isbf);
            stout(out, ob + 1, vy, isbf);
            stout(out, ob + 2, vz, isbf);
        } else {
            s_acc[so] = snew;
            unsigned short hi = f2bf(snew);
            s_hi[so] = hi;
            s_lo[so] = f2bf(snew - bf2f(hi));
            v_new[ib] = vx; v_new[ib + 1] = vy; v_new[ib + 2] = vz;
            vh_new[ib]     = f2bf(vx);
            vh_new[ib + 1] = f2bf(vy);
            vh_new[ib + 2] = f2bf(vz);
        }
    }
}

extern "C" void kernel_launch(void* const* d_in, const int* in_sizes, int n_in,
                              void* d_out, int out_size, void* d_ws, size_t ws_size,
                              hipStream_t stream) {
    const int N = in_sizes[0] / 3;
    const int E = in_sizes[1] / 2;
    const void* xyz  = d_in[0];
    const int*  nbr  = (const int*)d_in[1];
    const void* cg_s = d_in[2];
    const void* W1   = d_in[3];
    const void* b1   = d_in[4];
    const void* W2   = d_in[5];
    const void* b2   = d_in[6];
    const void* Wr   = d_in[7];
    const void* br   = d_in[8];

    int*   flag   = (int*)d_ws;
    float* s_acc  = (float*)((char*)d_ws + 64);
    float* vA     = s_acc  + (size_t)N * 128;
    float* vB     = vA     + (size_t)N * 384;
    float* unitv  = vB     + (size_t)N * 384;
    float* env    = unitv  + (size_t)E * 3;
    int*   rowptr = (int*)(env + E);
    int*   deg    = rowptr + (N + 16);
    int*   elist  = deg + N;
    unsigned short* rbfb = (unsigned short*)(elist + ((E + 7) & ~7));
    unsigned short* s_hi = rbfb + (size_t)E * NRBF;
    unsigned short* s_lo = s_hi + (size_t)N * 128;
    unsigned short* h_hi = s_lo + (size_t)N * 128;
    unsigned short* h_lo = h_hi + (size_t)N * 128;
    unsigned short* phi  = h_lo + (size_t)N * 128;
    unsigned short* vhA  = phi  + (size_t)N * 384;
    unsigned short* vhB  = vhA  + (size_t)N * 384;
    unsigned short* B1hi = vhB  + (size_t)N * 384;
    unsigned short* B1lo = B1hi + 3 * 4 * 8 * 64 * 8;
    unsigned short* B2hi = B1lo + 3 * 4 * 8 * 64 * 8;
    unsigned short* B2lo = B2hi + 3 * 4 * 24 * 64 * 8;

    detect_kernel<<<1, 64, 0, stream>>>(xyz, flag);
    hipMemsetAsync(deg, 0, (size_t)N * sizeof(int), stream);
    init_s_kernel<<<(N * 128 + 255) / 256, 256, 0, stream>>>(cg_s, s_acc, s_hi, s_lo, N * 128, flag);
    geom_kernel<<<(E + 255) / 256, 256, 0, stream>>>(xyz, nbr, unitv, rbfb, env, deg, E, flag);
    scan_kernel<<<1, 256, 0, stream>>>(deg, rowptr, N);
    scatter_kernel<<<(E + 255) / 256, 256, 0, stream>>>(nbr, env, deg, elist, E);
    prep_frags_kernel<<<(3 * 4 * 8 * 64 + 3 * 4 * 24 * 64 + 255) / 256, 256, 0, stream>>>(
        W1, W2, B1hi, B1lo, B2hi, B2lo, flag);

    const int gx = (N + 63) / 64;
    const int NODE_BLOCKS = 2048;
    for (int l = 0; l < 3; l++) {
        mfma_gemm<1, 0><<<dim3(gx, 2), 256, 0, stream>>>(
            s_hi, s_lo, B1hi + (size_t)l * 4 * 8 * 64 * 8, B1lo + (size_t)l * 4 * 8 * 64 * 8,
            b1, (size_t)l * 128, h_hi, h_lo, N, 128, flag);
        mfma_gemm<0, 1><<<dim3(gx, 6), 256, 0, stream>>>(
            h_hi, h_lo, B2hi + (size_t)l * 4 * 24 * 64 * 8, B2lo + (size_t)l * 4 * 24 * 64 * 8,
            b2, (size_t)l * 384, phi, (unsigned short*)nullptr, N, 384, flag);
        if (l == 0) {
            node_kernel<1, 0><<<NODE_BLOCKS, 128, 0, stream>>>(
                rowptr, elist, nbr, env, unitv, rbfb, phi,
                Wr, (size_t)l * NRBF * 384, br, (size_t)l * 384,
                vA, vhA, s_acc, s_hi, s_lo, vA, vhA, d_out, N, flag);
        } else if (l == 1) {
            node_kernel<0, 0><<<NODE_BLOCKS, 128, 0, stream>>>(
                rowptr, elist, nbr, env, unitv, rbfb, phi,
                Wr, (size_t)l * NRBF * 384, br, (size_t)l * 384,
                vA, vhA, s_acc, s_hi, s_lo, vB, vhB, d_out, N, flag);
        } else {
            node_kernel<0, 1><<<NODE_BLOCKS, 128, 0, stream>>>(
                rowptr, elist, nbr, env, unitv, rbfb, phi,
                Wr, (size_t)l * NRBF * 384, br, (size_t)l * 384,
                vB, vhB, s_acc, s_hi, s_lo, vB, vhB, d_out, N, flag);
        }
    }
}